// Round 5
// baseline (453.916 us; speedup 1.0000x reference)
//
#include <hip/hip_runtime.h>
#include <hip/hip_bf16.h>
#include <stdint.h>

// Problem constants
#define B_     8
#define CSW    241      // coarse_scores (B,241,241)
#define GW     121      // grid (B,121,121)
#define NPB    14641    // 121*121 per batch
#define KSEL   256
#define TOTG   117128   // 8*14641 gumbel count

// Output layout (floats): patches (8,256,3,64,64)=25165824,
// label_patches (8,256,1,64,64)=8388608, coords (8,256,2)=4096
#define PATCH_OFF   0
#define LABEL_OFF   25165824
#define COORD_OFF   33554432

// scratch inside d_out (floats), all dead before gather overwrites
#define FG_OFF    0           // 8*65536 = 524288 floats
#define CS_OFF    524288      // 8*58081 = 464648 floats
#define FLAT_OFF  988936      // 8*14641 = 117128 floats
#define MM_OFF    1106064     // 16 floats
#define KEY_OFF   1106080     // byte offset 4424320 (8-aligned); 8*14641 u64

// ---------------- fg = 4x4 stride-4 block mean of labels ----------------
// XLA CPU reduce order: flat sequential chain, row-major over (dy,dx), init 0.
__global__ void k_fg(const float* __restrict__ labels, float* __restrict__ fg) {
  int idx = blockIdx.x * 256 + threadIdx.x;          // < 8*256*256
  int b = idx >> 16; int rem = idx & 65535;
  int oy = rem >> 8; int ox = rem & 255;
  const float* p = labels + (size_t)b * 1048576 + (size_t)oy * 4096 + ox * 4;
  float acc = 0.0f;
  #pragma unroll
  for (int dy = 0; dy < 4; ++dy) {
    const float* r = p + dy * 1024;
    #pragma unroll
    for (int dx = 0; dx < 4; ++dx) acc = __fadd_rn(acc, r[dx]);
  }
  fg[idx] = __fdiv_rn(acc, 16.0f);                   // exact (pow2)
}

// ---------------- coarse_scores = 16x16 stride-1 window mean ----------------
// XLA CPU reduce_window: naive nested loop, flat sequential (wy outer, wx
// inner), init 0.
__global__ void k_cs(const float* __restrict__ fg, float* __restrict__ cs) {
  int idx = blockIdx.x * 256 + threadIdx.x;
  if (idx >= B_ * CSW * CSW) return;
  int b = idx / (CSW * CSW); int rem = idx % (CSW * CSW);
  int oy = rem / CSW; int ox = rem % CSW;
  const float* p = fg + (size_t)b * 65536 + (size_t)oy * 256 + ox;
  float acc = 0.0f;
  for (int wy = 0; wy < 16; ++wy) {
    const float* r = p + wy * 256;
    #pragma unroll
    for (int wx = 0; wx < 16; ++wx) acc = __fadd_rn(acc, r[wx]);
  }
  cs[idx] = __fdiv_rn(acc, 256.0f);                  // exact (pow2)
}

// ---------------- bilinear resize 241x241 -> 121x121, fp32 exact order ----------------
__global__ void k_resize(const float* __restrict__ cs, float* __restrict__ flat) {
  int idx = blockIdx.x * 256 + threadIdx.x;
  if (idx >= B_ * NPB) return;
  int b = idx / NPB; int rem = idx % NPB;
  int oy = rem / GW; int ox = rem % GW;
  const float SCALE = (float)(241.0 / 121.0);        // f64 const -> f32

  float cy = __fsub_rn(__fmul_rn(__fadd_rn((float)oy, 0.5f), SCALE), 0.5f);
  cy = fminf(fmaxf(cy, 0.0f), 240.0f);
  int y0 = (int)floorf(cy); int y1 = min(y0 + 1, 240);
  float wy = __fsub_rn(cy, (float)y0);

  float cx = __fsub_rn(__fmul_rn(__fadd_rn((float)ox, 0.5f), SCALE), 0.5f);
  cx = fminf(fmaxf(cx, 0.0f), 240.0f);
  int x0 = (int)floorf(cx); int x1 = min(x0 + 1, 240);
  float wx = __fsub_rn(cx, (float)x0);

  const float* base = cs + (size_t)b * (CSW * CSW);
  float v00 = base[y0 * CSW + x0];
  float v01 = base[y0 * CSW + x1];
  float v10 = base[y1 * CSW + x0];
  float v11 = base[y1 * CSW + x1];
  float omwx = __fsub_rn(1.0f, wx), omwy = __fsub_rn(1.0f, wy);
  float top = __fadd_rn(__fmul_rn(v00, omwx), __fmul_rn(v01, wx));
  float bot = __fadd_rn(__fmul_rn(v10, omwx), __fmul_rn(v11, wx));
  flat[idx] = __fadd_rn(__fmul_rn(top, omwy), __fmul_rn(bot, wy));
}

// ---------------- per-batch min/max (order-free, exact) ----------------
__global__ void k_minmax(const float* __restrict__ flat, float* __restrict__ mm) {
  __shared__ float smn[256], smx[256];
  int b = blockIdx.x, tid = threadIdx.x;
  float mn = 3.402823466e38f, mx = -3.402823466e38f;
  for (int j = tid; j < NPB; j += 256) {
    float v = flat[(size_t)b * NPB + j];
    mn = fminf(mn, v); mx = fmaxf(mx, v);
  }
  smn[tid] = mn; smx[tid] = mx; __syncthreads();
  for (int s = 128; s > 0; s >>= 1) {
    if (tid < s) {
      smn[tid] = fminf(smn[tid], smn[tid + s]);
      smx[tid] = fmaxf(smx[tid], smx[tid + s]);
    }
    __syncthreads();
  }
  if (tid == 0) { mm[b] = smn[0]; mm[8 + b] = smx[0]; }
}

// ---------------- threefry2x32, key (0,42), both output lanes ----------------
__device__ __forceinline__ void tf2(unsigned c0, unsigned c1,
                                    unsigned* o0, unsigned* o1) {
  const unsigned ks0 = 0u, ks1 = 42u, ks2 = 0x1BD11BDAu ^ 0u ^ 42u;
  unsigned x0 = c0 + ks0, x1 = c1 + ks1;
#define RND(r) { x0 += x1; x1 = (x1 << r) | (x1 >> (32 - r)); x1 ^= x0; }
  RND(13) RND(15) RND(26) RND(6)   x0 += ks1; x1 += ks2 + 1u;
  RND(17) RND(29) RND(16) RND(24)  x0 += ks2; x1 += ks0 + 2u;
  RND(13) RND(15) RND(26) RND(6)   x0 += ks0; x1 += ks1 + 3u;
  RND(17) RND(29) RND(16) RND(24)  x0 += ks1; x1 += ks2 + 4u;
  RND(13) RND(15) RND(26) RND(6)   x0 += ks2; x1 += ks0 + 5u;
#undef RND
  *o0 = x0; *o1 = x1;
}

// ---------------- scaled + gumbel -> sortable u64 keys ----------------
// JAX partitionable threefry (default >=0.4.30): counter-mode per element,
// bits[i] = x0 ^ x1 of threefry2x32(key, (hi32(i), lo32(i))) = (0, i).
__global__ void k_keys(const float* __restrict__ flat, const float* __restrict__ mm,
                       unsigned long long* __restrict__ keys) {
  int idx = blockIdx.x * 256 + threadIdx.x;
  if (idx >= TOTG) return;
  int b = idx / NPB; unsigned j = (unsigned)(idx % NPB);
  float smin = mm[b], smax = mm[8 + b];
  float rng = fmaxf(__fsub_rn(smax, smin), 1e-6f);
  float scaled = __fdiv_rn(__fdiv_rn(__fsub_rn(flat[idx], smin), rng), 0.1f);

  unsigned o0, o1;
  tf2(0u, (unsigned)idx, &o0, &o1);
  unsigned bits = o0 ^ o1;

  unsigned m = bits >> 9;
  float u = (m == 0u) ? 1.17549435e-38f
                      : __fsub_rn(__uint_as_float(0x3f800000u | m), 1.0f);
  // g = -log(-log(u)), each log evaluated in f64 then rounded to f32
  float l1 = (float)::log((double)u);
  float a  = -l1;
  float l2 = (float)::log((double)a);
  float g  = -l2;

  float tot = __fadd_rn(scaled, g);
  unsigned s = __float_as_uint(tot);
  unsigned o = (s & 0x80000000u) ? ~s : (s | 0x80000000u);   // monotone float order
  keys[idx] = ((unsigned long long)o << 32) | (unsigned long long)(j ^ 0xFFFFFFFFu);
}

// ---------------- per-batch top-256 (desc, stable) -> coords ----------------
__global__ void k_topk(const unsigned long long* __restrict__ keys,
                       float* __restrict__ coords) {
  __shared__ unsigned long long cand[4096];
  int b = blockIdx.x, tid = threadIdx.x;
  const unsigned long long* kb = keys + (size_t)b * NPB;

  unsigned long long loc[16];
  #pragma unroll
  for (int i = 0; i < 16; ++i) loc[i] = 0ull;

  for (int j = tid; j < NPB; j += 256) {
    unsigned long long v = kb[j];
    if (v > loc[15]) {
      loc[15] = v;
      #pragma unroll
      for (int i = 15; i > 0; --i) {            // one bubble pass = sorted insert
        unsigned long long hi = loc[i - 1], lo = loc[i];
        loc[i - 1] = hi > lo ? hi : lo;
        loc[i]     = hi > lo ? lo : hi;
      }
    }
  }
  #pragma unroll
  for (int i = 0; i < 16; ++i) cand[tid * 16 + i] = loc[i];
  __syncthreads();

  // bitonic sort ascending over 4096 unique keys
  for (int ksz = 2; ksz <= 4096; ksz <<= 1) {
    for (int jj = ksz >> 1; jj > 0; jj >>= 1) {
      for (int i = tid; i < 4096; i += 256) {
        int ixj = i ^ jj;
        if (ixj > i) {
          bool up = ((i & ksz) == 0);
          unsigned long long a = cand[i], c = cand[ixj];
          if ((a > c) == up) { cand[i] = c; cand[ixj] = a; }
        }
      }
      __syncthreads();
    }
  }

  // k-th largest at [4095-k]
  unsigned long long key = cand[4095 - tid];
  unsigned j = ((unsigned)(key & 0xFFFFFFFFull)) ^ 0xFFFFFFFFu;
  int row = j / GW, col = j % GW;
  coords[((size_t)b * KSEL + tid) * 2 + 0] = (float)(row * 8);
  coords[((size_t)b * KSEL + tid) * 2 + 1] = (float)(col * 8);
}

// ---------------- gather patches + label patches ----------------
__global__ void k_gather(const float* __restrict__ image, const float* __restrict__ labels,
                         float* __restrict__ out) {
  int bk = blockIdx.x;                 // b*256 + k
  int b = bk >> 8;
  const float* coords = out + COORD_OFF;
  int h = (int)coords[(size_t)bk * 2 + 0];
  int w = (int)coords[(size_t)bk * 2 + 1];

  const float* imgb = image + (size_t)b * 3145728;
  float* po = out + PATCH_OFF + (size_t)bk * 12288;
  for (int t = threadIdx.x; t < 12288; t += 256) {
    int c = t >> 12, rem = t & 4095, y = rem >> 6, x = rem & 63;
    po[t] = imgb[(size_t)c * 1048576 + (size_t)(h + y) * 1024 + (w + x)];
  }
  const float* labb = labels + (size_t)b * 1048576;
  float* lo = out + LABEL_OFF + (size_t)bk * 4096;
  for (int t = threadIdx.x; t < 4096; t += 256) {
    int y = t >> 6, x = t & 63;
    lo[t] = labb[(size_t)(h + y) * 1024 + (w + x)];
  }
}

extern "C" void kernel_launch(void* const* d_in, const int* in_sizes, int n_in,
                              void* d_out, int out_size, void* d_ws, size_t ws_size,
                              hipStream_t stream) {
  const float* image  = (const float*)d_in[0];   // (8,3,1024,1024)
  const float* labels = (const float*)d_in[1];   // (8,1,1024,1024)
  float* out = (float*)d_out;

  float* fg   = out + FG_OFF;
  float* cs   = out + CS_OFF;
  float* flat = out + FLAT_OFF;
  float* mm   = out + MM_OFF;
  unsigned long long* keys = (unsigned long long*)(out + KEY_OFF);
  float* coords = out + COORD_OFF;

  k_fg<<<2048, 256, 0, stream>>>(labels, fg);
  k_cs<<<(B_ * CSW * CSW + 255) / 256, 256, 0, stream>>>(fg, cs);
  k_resize<<<(TOTG + 255) / 256, 256, 0, stream>>>(cs, flat);
  k_minmax<<<B_, 256, 0, stream>>>(flat, mm);
  k_keys<<<(TOTG + 255) / 256, 256, 0, stream>>>(flat, mm, keys);
  k_topk<<<B_, 256, 0, stream>>>(keys, coords);
  k_gather<<<2048, 256, 0, stream>>>(image, labels, out);
}